// Round 3
// baseline (645.628 us; speedup 1.0000x reference)
//
#include <hip/hip_runtime.h>
#include <hip/hip_bf16.h>
#include <stdint.h>

#define N_TOK 8192
#define DIM   1024
#define HID   2048
#define NEXP  8

typedef __bf16 bf16x8 __attribute__((ext_vector_type(8)));
typedef float  f32x4  __attribute__((ext_vector_type(4)));
typedef unsigned short u16x8 __attribute__((ext_vector_type(8)));
typedef unsigned short u16x4 __attribute__((ext_vector_type(4)));

__device__ __forceinline__ float bits2f(unsigned short u) {
    union { unsigned int i; float f; } c; c.i = ((unsigned int)u) << 16; return c.f;
}
__device__ __forceinline__ unsigned short f2bfbits(float f) {
    __hip_bfloat16 h = __float2bfloat16(f);
    return *(unsigned short*)&h;
}

// ======================= small init =======================
__global__ void init_k(int* counts, float* Pacc, float* Facc) {
    int t = threadIdx.x;
    if (t < NEXP) { counts[t] = 0; Pacc[t] = 0.f; Facc[t] = 0.f; }
}

// ======================= router (fp32 in) =======================
// grid 256 x 256 threads; wave per token, 8 tokens per wave.
__global__ __launch_bounds__(256) void router_k(
    const float* __restrict__ x,
    const float* __restrict__ gate,
    int* __restrict__ counts, float* __restrict__ Pacc, float* __restrict__ Facc,
    int* __restrict__ tok_list, int* __restrict__ code, float* __restrict__ pw)
{
    __shared__ float gwS[NEXP][16][64];  // gwS[e][i][lane] = gate[e][lane*16+i]
    __shared__ float blkP[NEXP], blkF[NEXP];
    int tid = threadIdx.x;
    if (tid < NEXP) { blkP[tid] = 0.f; blkF[tid] = 0.f; }
    for (int idx = tid; idx < NEXP * DIM; idx += 256) {
        int e = idx >> 10, rem = idx & 1023, i = rem >> 6, l = rem & 63;
        gwS[e][i][l] = gate[e * DIM + l * 16 + i];
    }
    __syncthreads();
    int w = tid >> 6, lane = tid & 63;
    for (int it = 0; it < 8; ++it) {
        int token = blockIdx.x * 32 + w * 8 + it;
        const float* xr = x + (size_t)token * DIM + lane * 16;
        float xv[16];
        #pragma unroll
        for (int q = 0; q < 4; ++q) {
            float4 v = *(const float4*)(xr + q * 4);
            xv[q * 4 + 0] = v.x; xv[q * 4 + 1] = v.y; xv[q * 4 + 2] = v.z; xv[q * 4 + 3] = v.w;
        }
        float lg[NEXP];
        #pragma unroll
        for (int e = 0; e < NEXP; ++e) {
            float s = 0.f;
            #pragma unroll
            for (int i = 0; i < 16; ++i) s += xv[i] * gwS[e][i][lane];
            lg[e] = s;
        }
        #pragma unroll
        for (int off = 32; off > 0; off >>= 1)
            #pragma unroll
            for (int e = 0; e < NEXP; ++e) lg[e] += __shfl_xor(lg[e], off);
        float mx = lg[0]; int am = 0;
        #pragma unroll
        for (int e = 1; e < NEXP; ++e) if (lg[e] > mx) { mx = lg[e]; am = e; }
        float pr[NEXP], se = 0.f;
        #pragma unroll
        for (int e = 0; e < NEXP; ++e) { pr[e] = __expf(lg[e] - mx); se += pr[e]; }
        float inv = 1.f / se;
        #pragma unroll
        for (int e = 0; e < NEXP; ++e) pr[e] *= inv;
        float m2 = -1.f; int a2 = 0;
        #pragma unroll
        for (int e = 0; e < NEXP; ++e) if (e != am && pr[e] > m2) { m2 = pr[e]; a2 = e; }
        float psum = pr[am] + m2;
        float p0 = pr[am] / psum, p1 = m2 / psum;
        if (lane == 0) {
            int s0 = atomicAdd(&counts[am], 1);
            tok_list[am * N_TOK + s0] = token;
            code[token * 2] = (am << 13) | s0;
            pw[token * 2] = p0;
            int s1 = atomicAdd(&counts[a2], 1);
            tok_list[a2 * N_TOK + s1] = token;
            code[token * 2 + 1] = (a2 << 13) | s1;
            pw[token * 2 + 1] = p1;
            #pragma unroll
            for (int e = 0; e < NEXP; ++e) atomicAdd(&blkP[e], pr[e]);
            atomicAdd(&blkF[am], 1.f);
        }
    }
    __syncthreads();
    if (tid < NEXP) { atomicAdd(&Pacc[tid], blkP[tid]); atomicAdd(&Facc[tid], blkF[tid]); }
}

// ======================= finalize: prefix bases + aux loss (fp32 out) =======================
__global__ void finalize_k(const int* counts, int* basep, const float* Pacc, const float* Facc,
                           float* aux) {
    if (threadIdx.x == 0) {
        int b = 0;
        for (int e = 0; e < NEXP; ++e) { basep[e] = b; b += counts[e]; }
        float s = 0.f;
        for (int e = 0; e < NEXP; ++e) s += (Facc[e] * (1.f / 8192.f)) * (Pacc[e] * (1.f / 8192.f));
        aux[0] = 0.01f * 8.f * s;
    }
}

// ======================= weight transpose + fp32->bf16 convert =======================
// in: E x R x C fp32  ->  out: E x C x R bf16 bits.
__global__ __launch_bounds__(256) void transpose_cvt_k(const float* __restrict__ in,
                                                       unsigned short* __restrict__ out,
                                                       int R, int C)
{
    __shared__ unsigned short tile[64][72];  // +8 pad
    int e = blockIdx.z;
    const float* inp = in + (size_t)e * R * C;
    unsigned short* outp = out + (size_t)e * R * C;
    int r0 = blockIdx.y * 64, c0 = blockIdx.x * 64;
    int tid = threadIdx.x;
    {
        int r = tid >> 2;                 // 0..63
        int cseg = (tid & 3) * 16;        // 0,16,32,48
        const float* src = inp + (size_t)(r0 + r) * C + c0 + cseg;
        #pragma unroll
        for (int q = 0; q < 4; ++q) {
            float4 v = *(const float4*)(src + q * 4);
            tile[r][cseg + q * 4 + 0] = f2bfbits(v.x);
            tile[r][cseg + q * 4 + 1] = f2bfbits(v.y);
            tile[r][cseg + q * 4 + 2] = f2bfbits(v.z);
            tile[r][cseg + q * 4 + 3] = f2bfbits(v.w);
        }
    }
    __syncthreads();
    {
        int c = tid >> 2;                 // 0..63
        int rseg = (tid & 3) * 16;        // 0,16,32,48
        unsigned short* dst = outp + (size_t)(c0 + c) * R + r0 + rseg;
        #pragma unroll
        for (int h = 0; h < 2; ++h) {
            u16x8 o;
            #pragma unroll
            for (int i = 0; i < 8; ++i) o[i] = tile[rseg + h * 8 + i][c];
            *(u16x8*)(dst + h * 8) = o;
        }
    }
}

// ======================= grouped MFMA GEMM =======================
// O[basep[e]+slot][n] = act( sum_k Arow[slot][k] * BT[e][n][k] ), bf16 MFMA.
// GATHER: A rows come from fp32 x via tok_list (convert in registers).
// else:   A rows come from bf16 hidden rows [bas+slot].
// BT: bf16 [NEXP][N][K] k-innermost. Tile 128x128x32, 4 waves, 4x4 16x16x32 MFMA.
template<bool GATHER, bool RELU>
__global__ __launch_bounds__(256) void moe_gemm(
    const float* __restrict__ Af,            // fp32 source (GATHER)
    const unsigned short* __restrict__ Ab,   // bf16 source (!GATHER)
    const unsigned short* __restrict__ B,
    unsigned short* __restrict__ O,
    const int* __restrict__ counts,
    const int* __restrict__ basep,
    const int* __restrict__ tok_list,
    const int K, const int N)
{
    const int e = blockIdx.z;
    const int cnt = counts[e];
    const int m0 = blockIdx.y * 128;
    if (m0 >= cnt) return;
    const int n0 = blockIdx.x * 128;
    const int bas = basep[e];

    const int tid = threadIdx.x;
    const int w = tid >> 6, lane = tid & 63;
    const int wr = w >> 1, wc = w & 1;

    __shared__ __align__(16) unsigned short lds[8192];  // A tile [0,4096), B tile [4096,8192)

    // staging: thread stages rows r0i (A/B first half) and r1i (+64); k-chunk kc
    const int kc = (tid & 3) * 8;
    const int r0i = tid >> 2, r1i = 64 + (tid >> 2);
    const float *aF0 = nullptr, *aF1 = nullptr;
    const unsigned short *aB0 = nullptr, *aB1 = nullptr;
    if (GATHER) {
        int s0 = m0 + r0i, s1 = m0 + r1i;
        int t0 = (s0 < cnt) ? tok_list[e * N_TOK + s0] : 0;
        int t1 = (s1 < cnt) ? tok_list[e * N_TOK + s1] : 0;
        aF0 = Af + (size_t)t0 * K + kc;
        aF1 = Af + (size_t)t1 * K + kc;
    } else {
        int s0 = m0 + r0i; if (s0 > cnt - 1) s0 = cnt - 1;
        int s1 = m0 + r1i; if (s1 > cnt - 1) s1 = cnt - 1;
        aB0 = Ab + (size_t)(bas + s0) * K + kc;
        aB1 = Ab + (size_t)(bas + s1) * K + kc;
    }
    const unsigned short* Be = B + (size_t)e * N * K;
    const unsigned short* bRow0 = Be + (size_t)(n0 + r0i) * K + kc;
    const unsigned short* bRow1 = Be + (size_t)(n0 + r1i) * K + kc;

    f32x4 acc[4][4];
    #pragma unroll
    for (int i = 0; i < 4; ++i)
        #pragma unroll
        for (int j = 0; j < 4; ++j) acc[i][j] = f32x4{0.f, 0.f, 0.f, 0.f};

    const int quad = lane >> 4, ml = lane & 15;
    unsigned short* ldsA0 = &lds[tid * 8];
    unsigned short* ldsA1 = &lds[2048 + tid * 8];
    unsigned short* ldsB0 = &lds[4096 + tid * 8];
    unsigned short* ldsB1 = &lds[6144 + tid * 8];

    const int steps = K >> 5;
    for (int kt = 0; kt < steps; ++kt) {
        const int ko = kt * 32;
        u16x8 va0, va1;
        if (GATHER) {
            float4 p00 = *(const float4*)(aF0 + ko);
            float4 p01 = *(const float4*)(aF0 + ko + 4);
            float4 p10 = *(const float4*)(aF1 + ko);
            float4 p11 = *(const float4*)(aF1 + ko + 4);
            va0[0] = f2bfbits(p00.x); va0[1] = f2bfbits(p00.y); va0[2] = f2bfbits(p00.z); va0[3] = f2bfbits(p00.w);
            va0[4] = f2bfbits(p01.x); va0[5] = f2bfbits(p01.y); va0[6] = f2bfbits(p01.z); va0[7] = f2bfbits(p01.w);
            va1[0] = f2bfbits(p10.x); va1[1] = f2bfbits(p10.y); va1[2] = f2bfbits(p10.z); va1[3] = f2bfbits(p10.w);
            va1[4] = f2bfbits(p11.x); va1[5] = f2bfbits(p11.y); va1[6] = f2bfbits(p11.z); va1[7] = f2bfbits(p11.w);
        } else {
            va0 = *(const u16x8*)(aB0 + ko);
            va1 = *(const u16x8*)(aB1 + ko);
        }
        u16x8 vb0 = *(const u16x8*)(bRow0 + ko);
        u16x8 vb1 = *(const u16x8*)(bRow1 + ko);
        *(u16x8*)ldsA0 = va0;
        *(u16x8*)ldsA1 = va1;
        *(u16x8*)ldsB0 = vb0;
        *(u16x8*)ldsB1 = vb1;
        __syncthreads();
        bf16x8 af[4], bfr[4];
        #pragma unroll
        for (int i = 0; i < 4; ++i)
            af[i] = *(const bf16x8*)&lds[(wr * 64 + i * 16 + ml) * 32 + quad * 8];
        #pragma unroll
        for (int j = 0; j < 4; ++j)
            bfr[j] = *(const bf16x8*)&lds[4096 + (wc * 64 + j * 16 + ml) * 32 + quad * 8];
        #pragma unroll
        for (int i = 0; i < 4; ++i)
            #pragma unroll
            for (int j = 0; j < 4; ++j)
                acc[i][j] = __builtin_amdgcn_mfma_f32_16x16x32_bf16(af[i], bfr[j], acc[i][j], 0, 0, 0);
        __syncthreads();
    }

    // epilogue: C/D layout col = lane&15, row = quad*4 + reg
    #pragma unroll
    for (int i = 0; i < 4; ++i) {
        int rbase = wr * 64 + i * 16 + quad * 4;
        #pragma unroll
        for (int r = 0; r < 4; ++r) {
            int slot = m0 + rbase + r;
            if (slot < cnt) {
                unsigned short* orow = O + (size_t)(bas + slot) * N + n0 + wc * 64 + ml;
                #pragma unroll
                for (int j = 0; j < 4; ++j) {
                    float v = acc[i][j][r];
                    if (RELU) v = v > 0.f ? v : 0.f;
                    orow[j * 16] = f2bfbits(v);
                }
            }
        }
    }
}

// ======================= combine: out[t] = p0*Yp[row0] + p1*Yp[row1] (fp32 out) ============
__global__ __launch_bounds__(256) void combine_k(
    const unsigned short* __restrict__ Yp,
    const int* __restrict__ code, const float* __restrict__ pw,
    const int* __restrict__ basep,
    float* __restrict__ out)
{
    int t = blockIdx.x;
    int c0 = code[t * 2], c1 = code[t * 2 + 1];
    float p0 = pw[t * 2], p1 = pw[t * 2 + 1];
    size_t r0 = (size_t)(basep[c0 >> 13] + (c0 & 0x1FFF)) * DIM;
    size_t r1 = (size_t)(basep[c1 >> 13] + (c1 & 0x1FFF)) * DIM;
    int d = threadIdx.x * 4;
    u16x4 a = *(const u16x4*)(Yp + r0 + d);
    u16x4 b = *(const u16x4*)(Yp + r1 + d);
    float4 o;
    o.x = p0 * bits2f(a[0]) + p1 * bits2f(b[0]);
    o.y = p0 * bits2f(a[1]) + p1 * bits2f(b[1]);
    o.z = p0 * bits2f(a[2]) + p1 * bits2f(b[2]);
    o.w = p0 * bits2f(a[3]) + p1 * bits2f(b[3]);
    *(float4*)(out + (size_t)t * DIM + d) = o;
}

// ======================= launch =======================
extern "C" void kernel_launch(void* const* d_in, const int* in_sizes, int n_in,
                              void* d_out, int out_size, void* d_ws, size_t ws_size,
                              hipStream_t stream)
{
    const float* x    = (const float*)d_in[0];
    const float* gate = (const float*)d_in[1];
    const float* w1   = (const float*)d_in[2];
    const float* w2   = (const float*)d_in[3];
    float* out = (float*)d_out;

    char* ws = (char*)d_ws;
    int*   counts   = (int*)(ws + 0);
    int*   basep    = (int*)(ws + 256);
    float* Pacc     = (float*)(ws + 512);
    float* Facc     = (float*)(ws + 768);
    int*   tok_list = (int*)(ws + 1024);                      // 8*8192*4 = 256 KB
    int*   code     = (int*)(ws + 1024 + 262144);             // 64 KB
    float* pw       = (float*)(ws + 1024 + 262144 + 65536);   // 64 KB
    unsigned short* w1t    = (unsigned short*)(ws + (1 << 20));                         // 32 MB bf16
    unsigned short* w2t    = (unsigned short*)(ws + (1 << 20) + 33554432);              // 32 MB bf16
    unsigned short* hidden = (unsigned short*)(ws + (1 << 20) + 67108864);              // 64 MB bf16
    unsigned short* Yp     = (unsigned short*)(ws + (1 << 20) + 67108864 + 67108864);   // 32 MB bf16

    init_k<<<1, 64, 0, stream>>>(counts, Pacc, Facc);
    router_k<<<256, 256, 0, stream>>>(x, gate, counts, Pacc, Facc, tok_list, code, pw);
    finalize_k<<<1, 64, 0, stream>>>(counts, basep, Pacc, Facc, out + (size_t)N_TOK * DIM);
    transpose_cvt_k<<<dim3(HID / 64, DIM / 64, NEXP), 256, 0, stream>>>(w1, w1t, DIM, HID);
    transpose_cvt_k<<<dim3(DIM / 64, HID / 64, NEXP), 256, 0, stream>>>(w2, w2t, HID, DIM);
    moe_gemm<true, true><<<dim3(HID / 128, 64, NEXP), 256, 0, stream>>>(
        x, nullptr, w1t, hidden, counts, basep, tok_list, DIM, HID);
    moe_gemm<false, false><<<dim3(DIM / 128, 64, NEXP), 256, 0, stream>>>(
        nullptr, hidden, w2t, Yp, counts, basep, tok_list, HID, DIM);
    combine_k<<<N_TOK, 256, 0, stream>>>(Yp, code, pw, basep, out);
}

// Round 4
// 621.424 us; speedup vs baseline: 1.0389x; 1.0389x over previous
//
#include <hip/hip_runtime.h>
#include <hip/hip_bf16.h>
#include <stdint.h>

#define N_TOK 8192
#define DIM   1024
#define HID   2048
#define NEXP  8

typedef __bf16 bf16x8 __attribute__((ext_vector_type(8)));
typedef float  f32x4  __attribute__((ext_vector_type(4)));
typedef unsigned short u16x8 __attribute__((ext_vector_type(8)));
typedef unsigned short u16x4 __attribute__((ext_vector_type(4)));

__device__ __forceinline__ float bits2f(unsigned short u) {
    union { unsigned int i; float f; } c; c.i = ((unsigned int)u) << 16; return c.f;
}
__device__ __forceinline__ unsigned short f2bfbits(float f) {
    __hip_bfloat16 h = __float2bfloat16(f);
    return *(unsigned short*)&h;
}

// ---- async global->LDS, 16B per lane. Proper addrspace casts (compiler emits
// addrspacecast, which strips the flat aperture correctly — NOT int truncation).
__device__ __forceinline__ void load_lds16(const void* g, void* l) {
    __builtin_amdgcn_global_load_lds(
        (const __attribute__((address_space(1))) void*)g,
        (__attribute__((address_space(3))) void*)l,
        16, 0, 0);
}

// ======================= small init =======================
__global__ void init_k(int* counts, float* Pacc, float* Facc) {
    int t = threadIdx.x;
    if (t < NEXP) { counts[t] = 0; Pacc[t] = 0.f; Facc[t] = 0.f; }
}

// ======================= router (fp32 in) — 1 token per wave =======================
// grid 1024 x 512 threads (8 waves). Also emits xb = bf16(x) as a side product.
__global__ __launch_bounds__(512) void router_k(
    const float* __restrict__ x,
    const float* __restrict__ gate,
    int* __restrict__ counts, float* __restrict__ Pacc, float* __restrict__ Facc,
    int* __restrict__ tok_list, int* __restrict__ code, float* __restrict__ pw,
    unsigned short* __restrict__ xb)
{
    __shared__ float gwS[NEXP][16][64];  // gwS[e][i][lane] = gate[e][lane*16+i]
    __shared__ float blkP[NEXP], blkF[NEXP];
    int tid = threadIdx.x;
    if (tid < NEXP) { blkP[tid] = 0.f; blkF[tid] = 0.f; }
    for (int idx = tid; idx < NEXP * DIM; idx += 512) {
        int e = idx >> 10, rem = idx & 1023, i = rem >> 6, l = rem & 63;
        gwS[e][i][l] = gate[e * DIM + l * 16 + i];
    }
    __syncthreads();
    int w = tid >> 6, lane = tid & 63;
    int token = blockIdx.x * 8 + w;
    const float* xr = x + (size_t)token * DIM + lane * 16;
    float xv[16];
    #pragma unroll
    for (int q = 0; q < 4; ++q) {
        float4 v = *(const float4*)(xr + q * 4);
        xv[q * 4 + 0] = v.x; xv[q * 4 + 1] = v.y; xv[q * 4 + 2] = v.z; xv[q * 4 + 3] = v.w;
    }
    // fused fp32->bf16 convert of x (side product for GEMM1 gather)
    {
        u16x8 o0, o1;
        #pragma unroll
        for (int i = 0; i < 8; ++i) { o0[i] = f2bfbits(xv[i]); o1[i] = f2bfbits(xv[8 + i]); }
        unsigned short* dst = xb + (size_t)token * DIM + lane * 16;
        *(u16x8*)dst = o0;
        *(u16x8*)(dst + 8) = o1;
    }
    float lg[NEXP];
    #pragma unroll
    for (int e = 0; e < NEXP; ++e) {
        float s = 0.f;
        #pragma unroll
        for (int i = 0; i < 16; ++i) s += xv[i] * gwS[e][i][lane];
        lg[e] = s;
    }
    #pragma unroll
    for (int off = 32; off > 0; off >>= 1)
        #pragma unroll
        for (int e = 0; e < NEXP; ++e) lg[e] += __shfl_xor(lg[e], off);
    float mx = lg[0]; int am = 0;
    #pragma unroll
    for (int e = 1; e < NEXP; ++e) if (lg[e] > mx) { mx = lg[e]; am = e; }
    float pr[NEXP], se = 0.f;
    #pragma unroll
    for (int e = 0; e < NEXP; ++e) { pr[e] = __expf(lg[e] - mx); se += pr[e]; }
    float inv = 1.f / se;
    #pragma unroll
    for (int e = 0; e < NEXP; ++e) pr[e] *= inv;
    float m2 = -1.f; int a2 = 0;
    #pragma unroll
    for (int e = 0; e < NEXP; ++e) if (e != am && pr[e] > m2) { m2 = pr[e]; a2 = e; }
    float psum = pr[am] + m2;
    float p0 = pr[am] / psum, p1 = m2 / psum;
    if (lane == 0) {
        int s0 = atomicAdd(&counts[am], 1);
        tok_list[am * N_TOK + s0] = token;
        code[token * 2] = (am << 13) | s0;
        pw[token * 2] = p0;
        int s1 = atomicAdd(&counts[a2], 1);
        tok_list[a2 * N_TOK + s1] = token;
        code[token * 2 + 1] = (a2 << 13) | s1;
        pw[token * 2 + 1] = p1;
        #pragma unroll
        for (int e = 0; e < NEXP; ++e) atomicAdd(&blkP[e], pr[e]);
        atomicAdd(&blkF[am], 1.f);
    }
    __syncthreads();
    if (tid < NEXP) { atomicAdd(&Pacc[tid], blkP[tid]); atomicAdd(&Facc[tid], blkF[tid]); }
}

// ======================= finalize: prefix bases + aux loss (fp32 out) =======================
__global__ void finalize_k(const int* counts, int* basep, const float* Pacc, const float* Facc,
                           float* aux) {
    if (threadIdx.x == 0) {
        int b = 0;
        for (int e = 0; e < NEXP; ++e) { basep[e] = b; b += counts[e]; }
        float s = 0.f;
        for (int e = 0; e < NEXP; ++e) s += (Facc[e] * (1.f / 8192.f)) * (Pacc[e] * (1.f / 8192.f));
        aux[0] = 0.01f * 8.f * s;
    }
}

// ======================= weight transpose + fp32->bf16 convert =======================
// in: E x R x C fp32  ->  out: E x C x R bf16 bits.
__global__ __launch_bounds__(256) void transpose_cvt_k(const float* __restrict__ in,
                                                       unsigned short* __restrict__ out,
                                                       int R, int C)
{
    __shared__ unsigned short tile[64][72];  // +8 pad
    int e = blockIdx.z;
    const float* inp = in + (size_t)e * R * C;
    unsigned short* outp = out + (size_t)e * R * C;
    int r0 = blockIdx.y * 64, c0 = blockIdx.x * 64;
    int tid = threadIdx.x;
    {
        int r = tid >> 2;                 // 0..63
        int cseg = (tid & 3) * 16;        // 0,16,32,48
        const float* src = inp + (size_t)(r0 + r) * C + c0 + cseg;
        #pragma unroll
        for (int q = 0; q < 4; ++q) {
            float4 v = *(const float4*)(src + q * 4);
            tile[r][cseg + q * 4 + 0] = f2bfbits(v.x);
            tile[r][cseg + q * 4 + 1] = f2bfbits(v.y);
            tile[r][cseg + q * 4 + 2] = f2bfbits(v.z);
            tile[r][cseg + q * 4 + 3] = f2bfbits(v.w);
        }
    }
    __syncthreads();
    {
        int c = tid >> 2;                 // 0..63
        int rseg = (tid & 3) * 16;        // 0,16,32,48
        unsigned short* dst = outp + (size_t)(c0 + c) * R + r0 + rseg;
        #pragma unroll
        for (int h = 0; h < 2; ++h) {
            u16x8 o;
            #pragma unroll
            for (int i = 0; i < 8; ++i) o[i] = tile[rseg + h * 8 + i][c];
            *(u16x8*)(dst + h * 8) = o;
        }
    }
}

// ======================= grouped MFMA GEMM (async staging) =======================
// O[basep[e]+slot][n] = act( sum_k Arow[slot][k] * BT[e][n][k] ), bf16 MFMA.
// GATHER: A rows = xb[tok_list[e][slot]] (bf16). else: A rows = hidden[bas+slot].
// BT: bf16 [NEXP][N][K] k-innermost. Tile 128x128x32, 4 waves, 4x4 16x16x32 MFMA.
// Staging via global_load_lds width=16: thread tid covers LDS halfwords
// [tid*8, tid*8+8) per 64-row half => wave-uniform base + lane*16B. m97 structure.
template<bool GATHER, bool RELU>
__global__ __launch_bounds__(256) void moe_gemm(
    const unsigned short* __restrict__ A,
    const unsigned short* __restrict__ B,
    unsigned short* __restrict__ O,
    const int* __restrict__ counts,
    const int* __restrict__ basep,
    const int* __restrict__ tok_list,
    const int K, const int N)
{
    const int e = blockIdx.z;
    const int cnt = counts[e];
    const int m0 = blockIdx.y * 128;
    if (m0 >= cnt) return;
    const int n0 = blockIdx.x * 128;
    const int bas = basep[e];

    const int tid = threadIdx.x;
    const int w = tid >> 6, lane = tid & 63;
    const int wr = w >> 1, wc = w & 1;

    __shared__ __align__(16) unsigned short lds[8192];  // A tile [0,4096), B tile [4096,8192)

    // staging: thread stages rows r0i (first 64) and r1i (+64); k-chunk kc
    const int kc = (tid & 3) * 8;
    const int r0i = tid >> 2, r1i = 64 + (tid >> 2);
    const unsigned short *aRow0, *aRow1;
    if (GATHER) {
        int s0 = m0 + r0i, s1 = m0 + r1i;
        int t0 = (s0 < cnt) ? tok_list[e * N_TOK + s0] : 0;
        int t1 = (s1 < cnt) ? tok_list[e * N_TOK + s1] : 0;
        aRow0 = A + (size_t)t0 * K + kc;
        aRow1 = A + (size_t)t1 * K + kc;
    } else {
        int s0 = m0 + r0i; if (s0 > cnt - 1) s0 = cnt - 1;
        int s1 = m0 + r1i; if (s1 > cnt - 1) s1 = cnt - 1;
        aRow0 = A + (size_t)(bas + s0) * K + kc;
        aRow1 = A + (size_t)(bas + s1) * K + kc;
    }
    const unsigned short* Be = B + (size_t)e * N * K;
    const unsigned short* bRow0 = Be + (size_t)(n0 + r0i) * K + kc;
    const unsigned short* bRow1 = Be + (size_t)(n0 + r1i) * K + kc;

    f32x4 acc[4][4];
    #pragma unroll
    for (int i = 0; i < 4; ++i)
        #pragma unroll
        for (int j = 0; j < 4; ++j) acc[i][j] = f32x4{0.f, 0.f, 0.f, 0.f};

    const int quad = lane >> 4, ml = lane & 15;
    unsigned short* ldsA0 = &lds[tid * 8];
    unsigned short* ldsA1 = &lds[2048 + tid * 8];
    unsigned short* ldsB0 = &lds[4096 + tid * 8];
    unsigned short* ldsB1 = &lds[6144 + tid * 8];

    const int steps = K >> 5;
    for (int kt = 0; kt < steps; ++kt) {
        const int ko = kt * 32;
        load_lds16(aRow0 + ko, ldsA0);
        load_lds16(aRow1 + ko, ldsA1);
        load_lds16(bRow0 + ko, ldsB0);
        load_lds16(bRow1 + ko, ldsB1);
        __syncthreads();
        bf16x8 af[4], bfr[4];
        #pragma unroll
        for (int i = 0; i < 4; ++i)
            af[i] = *(const bf16x8*)&lds[(wr * 64 + i * 16 + ml) * 32 + quad * 8];
        #pragma unroll
        for (int j = 0; j < 4; ++j)
            bfr[j] = *(const bf16x8*)&lds[4096 + (wc * 64 + j * 16 + ml) * 32 + quad * 8];
        #pragma unroll
        for (int i = 0; i < 4; ++i)
            #pragma unroll
            for (int j = 0; j < 4; ++j)
                acc[i][j] = __builtin_amdgcn_mfma_f32_16x16x32_bf16(af[i], bfr[j], acc[i][j], 0, 0, 0);
        __syncthreads();
    }

    // epilogue: C/D layout col = lane&15, row = quad*4 + reg
    #pragma unroll
    for (int i = 0; i < 4; ++i) {
        int rbase = wr * 64 + i * 16 + quad * 4;
        #pragma unroll
        for (int r = 0; r < 4; ++r) {
            int slot = m0 + rbase + r;
            if (slot < cnt) {
                unsigned short* orow = O + (size_t)(bas + slot) * N + n0 + wc * 64 + ml;
                #pragma unroll
                for (int j = 0; j < 4; ++j) {
                    float v = acc[i][j][r];
                    if (RELU) v = v > 0.f ? v : 0.f;
                    orow[j * 16] = f2bfbits(v);
                }
            }
        }
    }
}

// ======================= combine: out[t] = p0*Yp[row0] + p1*Yp[row1] (fp32 out) ============
__global__ __launch_bounds__(256) void combine_k(
    const unsigned short* __restrict__ Yp,
    const int* __restrict__ code, const float* __restrict__ pw,
    const int* __restrict__ basep,
    float* __restrict__ out)
{
    int t = blockIdx.x;
    int c0 = code[t * 2], c1 = code[t * 2 + 1];
    float p0 = pw[t * 2], p1 = pw[t * 2 + 1];
    size_t r0 = (size_t)(basep[c0 >> 13] + (c0 & 0x1FFF)) * DIM;
    size_t r1 = (size_t)(basep[c1 >> 13] + (c1 & 0x1FFF)) * DIM;
    int d = threadIdx.x * 4;
    u16x4 a = *(const u16x4*)(Yp + r0 + d);
    u16x4 b = *(const u16x4*)(Yp + r1 + d);
    float4 o;
    o.x = p0 * bits2f(a[0]) + p1 * bits2f(b[0]);
    o.y = p0 * bits2f(a[1]) + p1 * bits2f(b[1]);
    o.z = p0 * bits2f(a[2]) + p1 * bits2f(b[2]);
    o.w = p0 * bits2f(a[3]) + p1 * bits2f(b[3]);
    *(float4*)(out + (size_t)t * DIM + d) = o;
}

// ======================= launch =======================
extern "C" void kernel_launch(void* const* d_in, const int* in_sizes, int n_in,
                              void* d_out, int out_size, void* d_ws, size_t ws_size,
                              hipStream_t stream)
{
    const float* x    = (const float*)d_in[0];
    const float* gate = (const float*)d_in[1];
    const float* w1   = (const float*)d_in[2];
    const float* w2   = (const float*)d_in[3];
    float* out = (float*)d_out;

    char* ws = (char*)d_ws;
    int*   counts   = (int*)(ws + 0);
    int*   basep    = (int*)(ws + 256);
    float* Pacc     = (float*)(ws + 512);
    float* Facc     = (float*)(ws + 768);
    int*   tok_list = (int*)(ws + 1024);                      // 8*8192*4 = 256 KB
    int*   code     = (int*)(ws + 1024 + 262144);             // 64 KB
    float* pw       = (float*)(ws + 1024 + 262144 + 65536);   // 64 KB
    unsigned short* w1t    = (unsigned short*)(ws + (1 << 20));                         // 32 MB bf16
    unsigned short* w2t    = (unsigned short*)(ws + (1 << 20) + 33554432);              // 32 MB bf16
    unsigned short* hidden = (unsigned short*)(ws + (1 << 20) + 67108864);              // 64 MB bf16
    // xb (16 MB) aliases the Yp region (32 MB): xb is dead before GEMM2 writes Yp.
    unsigned short* YpXb   = (unsigned short*)(ws + (1 << 20) + 67108864 + 67108864);   // 32 MB bf16
    unsigned short* xb     = YpXb;
    unsigned short* Yp     = YpXb;

    init_k<<<1, 64, 0, stream>>>(counts, Pacc, Facc);
    router_k<<<1024, 512, 0, stream>>>(x, gate, counts, Pacc, Facc, tok_list, code, pw, xb);
    finalize_k<<<1, 64, 0, stream>>>(counts, basep, Pacc, Facc, out + (size_t)N_TOK * DIM);
    transpose_cvt_k<<<dim3(HID / 64, DIM / 64, NEXP), 256, 0, stream>>>(w1, w1t, DIM, HID);
    transpose_cvt_k<<<dim3(DIM / 64, HID / 64, NEXP), 256, 0, stream>>>(w2, w2t, HID, DIM);
    moe_gemm<true, true><<<dim3(HID / 128, 64, NEXP), 256, 0, stream>>>(
        xb, w1t, hidden, counts, basep, tok_list, DIM, HID);
    moe_gemm<false, false><<<dim3(DIM / 128, 64, NEXP), 256, 0, stream>>>(
        hidden, w2t, Yp, counts, basep, tok_list, HID, DIM);
    combine_k<<<N_TOK, 256, 0, stream>>>(Yp, code, pw, basep, out);
}

// Round 5
// 446.662 us; speedup vs baseline: 1.4455x; 1.3913x over previous
//
#include <hip/hip_runtime.h>
#include <hip/hip_bf16.h>
#include <stdint.h>

#define N_TOK 8192
#define DIM   1024
#define HID   2048
#define NEXP  8
#define RB    256   // route blocks (32 tokens each)

typedef __bf16 bf16x8 __attribute__((ext_vector_type(8)));
typedef float  f32x4  __attribute__((ext_vector_type(4)));
typedef unsigned short u16x8 __attribute__((ext_vector_type(8)));
typedef unsigned short u16x4 __attribute__((ext_vector_type(4)));

__device__ __forceinline__ float bits2f(unsigned short u) {
    union { unsigned int i; float f; } c; c.i = ((unsigned int)u) << 16; return c.f;
}
__device__ __forceinline__ unsigned short f2bfbits(float f) {
    __hip_bfloat16 h = __float2bfloat16(f);
    return *(unsigned short*)&h;
}

// ---- async global->LDS, 16B per lane ----
__device__ __forceinline__ void load_lds16(const void* g, void* l) {
    __builtin_amdgcn_global_load_lds(
        (const __attribute__((address_space(1))) void*)g,
        (__attribute__((address_space(3))) void*)l,
        16, 0, 0);
}

// ======================= phase 1: route (no global atomics) =======================
// 256 blocks x 512 thr; wave per token-quad (32 tokens/block). Emits per-token
// expert pair + renorm probs + bf16(x); per-block histograms via LDS only.
__global__ __launch_bounds__(512) void route_k(
    const float* __restrict__ x,
    const float* __restrict__ gate,
    int* __restrict__ epack, float* __restrict__ pw,
    unsigned short* __restrict__ xb,
    int* __restrict__ H0, int* __restrict__ H1, float* __restrict__ Pblk)
{
    __shared__ float gwS[NEXP][16][64];  // gwS[e][i][lane] = gate[e][lane*16+i]
    __shared__ int h0S[NEXP], h1S[NEXP];
    __shared__ float pS[NEXP];
    int tid = threadIdx.x;
    if (tid < NEXP) { h0S[tid] = 0; h1S[tid] = 0; pS[tid] = 0.f; }
    for (int idx = tid; idx < NEXP * DIM; idx += 512) {
        int e = idx >> 10, rem = idx & 1023, i = rem >> 6, l = rem & 63;
        gwS[e][i][l] = gate[e * DIM + l * 16 + i];
    }
    __syncthreads();
    int w = tid >> 6, lane = tid & 63;
    float prAcc[NEXP];
    #pragma unroll
    for (int e = 0; e < NEXP; ++e) prAcc[e] = 0.f;
    for (int it = 0; it < 4; ++it) {
        int token = blockIdx.x * 32 + w * 4 + it;
        const float* xr = x + (size_t)token * DIM + lane * 16;
        float xv[16];
        #pragma unroll
        for (int q = 0; q < 4; ++q) {
            float4 v = *(const float4*)(xr + q * 4);
            xv[q * 4 + 0] = v.x; xv[q * 4 + 1] = v.y; xv[q * 4 + 2] = v.z; xv[q * 4 + 3] = v.w;
        }
        {   // fused fp32->bf16 of x
            u16x8 o0, o1;
            #pragma unroll
            for (int i = 0; i < 8; ++i) { o0[i] = f2bfbits(xv[i]); o1[i] = f2bfbits(xv[8 + i]); }
            unsigned short* dst = xb + (size_t)token * DIM + lane * 16;
            *(u16x8*)dst = o0;
            *(u16x8*)(dst + 8) = o1;
        }
        float lg[NEXP];
        #pragma unroll
        for (int e = 0; e < NEXP; ++e) {
            float s = 0.f;
            #pragma unroll
            for (int i = 0; i < 16; ++i) s += xv[i] * gwS[e][i][lane];
            lg[e] = s;
        }
        #pragma unroll
        for (int off = 32; off > 0; off >>= 1)
            #pragma unroll
            for (int e = 0; e < NEXP; ++e) lg[e] += __shfl_xor(lg[e], off);
        float mx = lg[0]; int am = 0;
        #pragma unroll
        for (int e = 1; e < NEXP; ++e) if (lg[e] > mx) { mx = lg[e]; am = e; }
        float pr[NEXP], se = 0.f;
        #pragma unroll
        for (int e = 0; e < NEXP; ++e) { pr[e] = __expf(lg[e] - mx); se += pr[e]; }
        float inv = 1.f / se;
        #pragma unroll
        for (int e = 0; e < NEXP; ++e) pr[e] *= inv;
        float m2 = -1.f; int a2 = 0;
        #pragma unroll
        for (int e = 0; e < NEXP; ++e) if (e != am && pr[e] > m2) { m2 = pr[e]; a2 = e; }
        float psum = pr[am] + m2;
        if (lane == 0) {
            epack[token] = am | (a2 << 4);
            pw[token * 2] = pr[am] / psum;
            pw[token * 2 + 1] = m2 / psum;
            atomicAdd(&h0S[am], 1);   // LDS-scope, cheap
            atomicAdd(&h1S[a2], 1);
            #pragma unroll
            for (int e = 0; e < NEXP; ++e) prAcc[e] += pr[e];
        }
    }
    if (lane == 0) {
        #pragma unroll
        for (int e = 0; e < NEXP; ++e) atomicAdd(&pS[e], prAcc[e]);
    }
    __syncthreads();
    if (tid < NEXP) {
        H0[blockIdx.x * NEXP + tid] = h0S[tid];
        H1[blockIdx.x * NEXP + tid] = h1S[tid];
        Pblk[blockIdx.x * NEXP + tid] = pS[tid];
    }
}

// ======================= phase 2: scan (1 block) =======================
// Per-expert exclusive prefix of (H0+H1) over blocks -> bbL; totals -> counts/basep;
// aux loss from F=sum(H0), P=sum(Pblk).
__global__ __launch_bounds__(256) void scan_k(
    const int* __restrict__ H0, const int* __restrict__ H1,
    const float* __restrict__ Pblk,
    int* __restrict__ bbL, int* __restrict__ counts, int* __restrict__ basep,
    float* __restrict__ aux)
{
    __shared__ int h0S[RB * NEXP], h1S[RB * NEXP], bbS[RB * NEXP];
    __shared__ float pSh[RB * NEXP];
    __shared__ int cS[NEXP], fS[NEXP];
    __shared__ float psS[NEXP];
    int tid = threadIdx.x;
    for (int i = tid; i < RB * NEXP; i += 256) { h0S[i] = H0[i]; h1S[i] = H1[i]; pSh[i] = Pblk[i]; }
    __syncthreads();
    if (tid < NEXP) {
        int run = 0, f = 0; float p = 0.f;
        for (int b = 0; b < RB; ++b) {
            int i = b * NEXP + tid;
            bbS[i] = run;
            run += h0S[i] + h1S[i];
            f += h0S[i];
            p += pSh[i];
        }
        cS[tid] = run; fS[tid] = f; psS[tid] = p;
        counts[tid] = run;
    }
    __syncthreads();
    if (tid == 0) {
        int b = 0; float s = 0.f;
        for (int e = 0; e < NEXP; ++e) {
            basep[e] = b; b += cS[e];
            s += (fS[e] * (1.f / 8192.f)) * (psS[e] * (1.f / 8192.f));
        }
        aux[0] = 0.01f * 8.f * s;
    }
    __syncthreads();
    for (int i = tid; i < RB * NEXP; i += 256) bbL[i] = bbS[i];
}

// ======================= phase 3: scatter (ballot ranking, no atomics) ==============
// 64 blocks x 256 thr; wave per 32-token group. lane -> (token=g*32+lane/2, j=lane&1).
__global__ __launch_bounds__(256) void scatter_k(
    const int* __restrict__ epack, const int* __restrict__ bbL,
    int* __restrict__ tok_list, int* __restrict__ code)
{
    int tid = threadIdx.x;
    int w = tid >> 6, lane = tid & 63;
    int g = blockIdx.x * 4 + w;
    int token = g * 32 + (lane >> 1);
    int ep = epack[token];
    int e = (lane & 1) ? ((ep >> 4) & 0xF) : (ep & 0xF);
    unsigned long long lower = (lane == 0) ? 0ull : ((~0ull) >> (64 - lane));
    unsigned long long mymask = 0;
    #pragma unroll
    for (int ee = 0; ee < NEXP; ++ee) {
        unsigned long long m = __ballot(e == ee);
        if (ee == e) mymask = m;
    }
    int rank = __popcll(mymask & lower);
    int slot = bbL[g * NEXP + e] + rank;     // local slot within expert e
    tok_list[e * N_TOK + slot] = token;
    code[token * 2 + (lane & 1)] = (e << 13) | slot;
}

// ======================= weight transpose + fp32->bf16 convert =======================
__global__ __launch_bounds__(256) void transpose_cvt_k(const float* __restrict__ in,
                                                       unsigned short* __restrict__ out,
                                                       int R, int C)
{
    __shared__ unsigned short tile[64][72];  // +8 pad
    int e = blockIdx.z;
    const float* inp = in + (size_t)e * R * C;
    unsigned short* outp = out + (size_t)e * R * C;
    int r0 = blockIdx.y * 64, c0 = blockIdx.x * 64;
    int tid = threadIdx.x;
    {
        int r = tid >> 2;
        int cseg = (tid & 3) * 16;
        const float* src = inp + (size_t)(r0 + r) * C + c0 + cseg;
        #pragma unroll
        for (int q = 0; q < 4; ++q) {
            float4 v = *(const float4*)(src + q * 4);
            tile[r][cseg + q * 4 + 0] = f2bfbits(v.x);
            tile[r][cseg + q * 4 + 1] = f2bfbits(v.y);
            tile[r][cseg + q * 4 + 2] = f2bfbits(v.z);
            tile[r][cseg + q * 4 + 3] = f2bfbits(v.w);
        }
    }
    __syncthreads();
    {
        int c = tid >> 2;
        int rseg = (tid & 3) * 16;
        unsigned short* dst = outp + (size_t)(c0 + c) * R + r0 + rseg;
        #pragma unroll
        for (int h = 0; h < 2; ++h) {
            u16x8 o;
            #pragma unroll
            for (int i = 0; i < 8; ++i) o[i] = tile[rseg + h * 8 + i][c];
            *(u16x8*)(dst + h * 8) = o;
        }
    }
}

// ======================= grouped MFMA GEMM (async staging) =======================
template<bool GATHER, bool RELU>
__global__ __launch_bounds__(256) void moe_gemm(
    const unsigned short* __restrict__ A,
    const unsigned short* __restrict__ B,
    unsigned short* __restrict__ O,
    const int* __restrict__ counts,
    const int* __restrict__ basep,
    const int* __restrict__ tok_list,
    const int K, const int N)
{
    const int e = blockIdx.z;
    const int cnt = counts[e];
    const int m0 = blockIdx.y * 128;
    if (m0 >= cnt) return;
    const int n0 = blockIdx.x * 128;
    const int bas = basep[e];

    const int tid = threadIdx.x;
    const int w = tid >> 6, lane = tid & 63;
    const int wr = w >> 1, wc = w & 1;

    __shared__ __align__(16) unsigned short lds[8192];

    const int kc = (tid & 3) * 8;
    const int r0i = tid >> 2, r1i = 64 + (tid >> 2);
    const unsigned short *aRow0, *aRow1;
    if (GATHER) {
        int s0 = m0 + r0i, s1 = m0 + r1i;
        int t0 = (s0 < cnt) ? tok_list[e * N_TOK + s0] : 0;
        int t1 = (s1 < cnt) ? tok_list[e * N_TOK + s1] : 0;
        aRow0 = A + (size_t)t0 * K + kc;
        aRow1 = A + (size_t)t1 * K + kc;
    } else {
        int s0 = m0 + r0i; if (s0 > cnt - 1) s0 = cnt - 1;
        int s1 = m0 + r1i; if (s1 > cnt - 1) s1 = cnt - 1;
        aRow0 = A + (size_t)(bas + s0) * K + kc;
        aRow1 = A + (size_t)(bas + s1) * K + kc;
    }
    const unsigned short* Be = B + (size_t)e * N * K;
    const unsigned short* bRow0 = Be + (size_t)(n0 + r0i) * K + kc;
    const unsigned short* bRow1 = Be + (size_t)(n0 + r1i) * K + kc;

    f32x4 acc[4][4];
    #pragma unroll
    for (int i = 0; i < 4; ++i)
        #pragma unroll
        for (int j = 0; j < 4; ++j) acc[i][j] = f32x4{0.f, 0.f, 0.f, 0.f};

    const int quad = lane >> 4, ml = lane & 15;
    unsigned short* ldsA0 = &lds[tid * 8];
    unsigned short* ldsA1 = &lds[2048 + tid * 8];
    unsigned short* ldsB0 = &lds[4096 + tid * 8];
    unsigned short* ldsB1 = &lds[6144 + tid * 8];

    const int steps = K >> 5;
    for (int kt = 0; kt < steps; ++kt) {
        const int ko = kt * 32;
        load_lds16(aRow0 + ko, ldsA0);
        load_lds16(aRow1 + ko, ldsA1);
        load_lds16(bRow0 + ko, ldsB0);
        load_lds16(bRow1 + ko, ldsB1);
        __syncthreads();
        bf16x8 af[4], bfr[4];
        #pragma unroll
        for (int i = 0; i < 4; ++i)
            af[i] = *(const bf16x8*)&lds[(wr * 64 + i * 16 + ml) * 32 + quad * 8];
        #pragma unroll
        for (int j = 0; j < 4; ++j)
            bfr[j] = *(const bf16x8*)&lds[4096 + (wc * 64 + j * 16 + ml) * 32 + quad * 8];
        #pragma unroll
        for (int i = 0; i < 4; ++i)
            #pragma unroll
            for (int j = 0; j < 4; ++j)
                acc[i][j] = __builtin_amdgcn_mfma_f32_16x16x32_bf16(af[i], bfr[j], acc[i][j], 0, 0, 0);
        __syncthreads();
    }

    #pragma unroll
    for (int i = 0; i < 4; ++i) {
        int rbase = wr * 64 + i * 16 + quad * 4;
        #pragma unroll
        for (int r = 0; r < 4; ++r) {
            int slot = m0 + rbase + r;
            if (slot < cnt) {
                unsigned short* orow = O + (size_t)(bas + slot) * N + n0 + wc * 64 + ml;
                #pragma unroll
                for (int j = 0; j < 4; ++j) {
                    float v = acc[i][j][r];
                    if (RELU) v = v > 0.f ? v : 0.f;
                    orow[j * 16] = f2bfbits(v);
                }
            }
        }
    }
}

// ======================= combine =======================
__global__ __launch_bounds__(256) void combine_k(
    const unsigned short* __restrict__ Yp,
    const int* __restrict__ code, const float* __restrict__ pw,
    const int* __restrict__ basep,
    float* __restrict__ out)
{
    int t = blockIdx.x;
    int c0 = code[t * 2], c1 = code[t * 2 + 1];
    float p0 = pw[t * 2], p1 = pw[t * 2 + 1];
    size_t r0 = (size_t)(basep[c0 >> 13] + (c0 & 0x1FFF)) * DIM;
    size_t r1 = (size_t)(basep[c1 >> 13] + (c1 & 0x1FFF)) * DIM;
    int d = threadIdx.x * 4;
    u16x4 a = *(const u16x4*)(Yp + r0 + d);
    u16x4 b = *(const u16x4*)(Yp + r1 + d);
    float4 o;
    o.x = p0 * bits2f(a[0]) + p1 * bits2f(b[0]);
    o.y = p0 * bits2f(a[1]) + p1 * bits2f(b[1]);
    o.z = p0 * bits2f(a[2]) + p1 * bits2f(b[2]);
    o.w = p0 * bits2f(a[3]) + p1 * bits2f(b[3]);
    *(float4*)(out + (size_t)t * DIM + d) = o;
}

// ======================= launch =======================
extern "C" void kernel_launch(void* const* d_in, const int* in_sizes, int n_in,
                              void* d_out, int out_size, void* d_ws, size_t ws_size,
                              hipStream_t stream)
{
    const float* x    = (const float*)d_in[0];
    const float* gate = (const float*)d_in[1];
    const float* w1   = (const float*)d_in[2];
    const float* w2   = (const float*)d_in[3];
    float* out = (float*)d_out;

    char* ws = (char*)d_ws;
    int*   counts   = (int*)(ws + 0);                         // 32 B
    int*   basep    = (int*)(ws + 256);
    int*   epack    = (int*)(ws + 1024);                      // 32 KB
    int*   H0       = (int*)(ws + 1024 + 32768);              // 8 KB
    int*   H1       = (int*)(ws + 1024 + 40960);              // 8 KB
    float* Pblk     = (float*)(ws + 1024 + 49152);            // 8 KB
    int*   bbL      = (int*)(ws + 1024 + 57344);              // 8 KB
    int*   tok_list = (int*)(ws + 131072);                    // 256 KB
    int*   code     = (int*)(ws + 131072 + 262144);           // 64 KB
    float* pw       = (float*)(ws + 131072 + 262144 + 65536); // 64 KB
    unsigned short* w1t    = (unsigned short*)(ws + (1 << 20));                         // 32 MB bf16
    unsigned short* w2t    = (unsigned short*)(ws + (1 << 20) + 33554432);              // 32 MB bf16
    unsigned short* hidden = (unsigned short*)(ws + (1 << 20) + 67108864);              // 64 MB bf16
    unsigned short* YpXb   = (unsigned short*)(ws + (1 << 20) + 67108864 + 67108864);   // 32 MB bf16
    unsigned short* xb     = YpXb;  // xb dead before GEMM2 writes Yp
    unsigned short* Yp     = YpXb;

    route_k<<<RB, 512, 0, stream>>>(x, gate, epack, pw, xb, H0, H1, Pblk);
    scan_k<<<1, 256, 0, stream>>>(H0, H1, Pblk, bbL, counts, basep, out + (size_t)N_TOK * DIM);
    scatter_k<<<64, 256, 0, stream>>>(epack, bbL, tok_list, code);
    transpose_cvt_k<<<dim3(HID / 64, DIM / 64, NEXP), 256, 0, stream>>>(w1, w1t, DIM, HID);
    transpose_cvt_k<<<dim3(DIM / 64, HID / 64, NEXP), 256, 0, stream>>>(w2, w2t, HID, DIM);
    moe_gemm<true, true><<<dim3(HID / 128, 64, NEXP), 256, 0, stream>>>(
        xb, w1t, hidden, counts, basep, tok_list, DIM, HID);
    moe_gemm<false, false><<<dim3(DIM / 128, 64, NEXP), 256, 0, stream>>>(
        hidden, w2t, Yp, counts, basep, tok_list, HID, DIM);
    combine_k<<<N_TOK, 256, 0, stream>>>(Yp, code, pw, basep, out);
}

// Round 6
// 428.429 us; speedup vs baseline: 1.5070x; 1.0426x over previous
//
#include <hip/hip_runtime.h>
#include <hip/hip_bf16.h>
#include <stdint.h>

#define N_TOK 8192
#define DIM   1024
#define HID   2048
#define NEXP  8
#define RB    256   // route blocks (32 tokens each)

typedef __bf16 bf16x8 __attribute__((ext_vector_type(8)));
typedef float  f32x4  __attribute__((ext_vector_type(4)));
typedef unsigned short u16x8 __attribute__((ext_vector_type(8)));
typedef unsigned short u16x4 __attribute__((ext_vector_type(4)));

__device__ __forceinline__ float bits2f(unsigned short u) {
    union { unsigned int i; float f; } c; c.i = ((unsigned int)u) << 16; return c.f;
}
__device__ __forceinline__ unsigned short f2bfbits(float f) {
    __hip_bfloat16 h = __float2bfloat16(f);
    return *(unsigned short*)&h;
}

// ---- async global->LDS, 16B per lane ----
__device__ __forceinline__ void load_lds16(const void* g, void* l) {
    __builtin_amdgcn_global_load_lds(
        (const __attribute__((address_space(1))) void*)g,
        (__attribute__((address_space(3))) void*)l,
        16, 0, 0);
}

// ======================= phase 1: route (no global atomics) =======================
__global__ __launch_bounds__(512) void route_k(
    const float* __restrict__ x,
    const float* __restrict__ gate,
    int* __restrict__ epack, float* __restrict__ pw,
    unsigned short* __restrict__ xb,
    int* __restrict__ H0, int* __restrict__ H1, float* __restrict__ Pblk)
{
    __shared__ float gwS[NEXP][16][64];
    __shared__ int h0S[NEXP], h1S[NEXP];
    __shared__ float pS[NEXP];
    int tid = threadIdx.x;
    if (tid < NEXP) { h0S[tid] = 0; h1S[tid] = 0; pS[tid] = 0.f; }
    for (int idx = tid; idx < NEXP * DIM; idx += 512) {
        int e = idx >> 10, rem = idx & 1023, i = rem >> 6, l = rem & 63;
        gwS[e][i][l] = gate[e * DIM + l * 16 + i];
    }
    __syncthreads();
    int w = tid >> 6, lane = tid & 63;
    float prAcc[NEXP];
    #pragma unroll
    for (int e = 0; e < NEXP; ++e) prAcc[e] = 0.f;
    for (int it = 0; it < 4; ++it) {
        int token = blockIdx.x * 32 + w * 4 + it;
        const float* xr = x + (size_t)token * DIM + lane * 16;
        float xv[16];
        #pragma unroll
        for (int q = 0; q < 4; ++q) {
            float4 v = *(const float4*)(xr + q * 4);
            xv[q * 4 + 0] = v.x; xv[q * 4 + 1] = v.y; xv[q * 4 + 2] = v.z; xv[q * 4 + 3] = v.w;
        }
        {
            u16x8 o0, o1;
            #pragma unroll
            for (int i = 0; i < 8; ++i) { o0[i] = f2bfbits(xv[i]); o1[i] = f2bfbits(xv[8 + i]); }
            unsigned short* dst = xb + (size_t)token * DIM + lane * 16;
            *(u16x8*)dst = o0;
            *(u16x8*)(dst + 8) = o1;
        }
        float lg[NEXP];
        #pragma unroll
        for (int e = 0; e < NEXP; ++e) {
            float s = 0.f;
            #pragma unroll
            for (int i = 0; i < 16; ++i) s += xv[i] * gwS[e][i][lane];
            lg[e] = s;
        }
        #pragma unroll
        for (int off = 32; off > 0; off >>= 1)
            #pragma unroll
            for (int e = 0; e < NEXP; ++e) lg[e] += __shfl_xor(lg[e], off);
        float mx = lg[0]; int am = 0;
        #pragma unroll
        for (int e = 1; e < NEXP; ++e) if (lg[e] > mx) { mx = lg[e]; am = e; }
        float pr[NEXP], se = 0.f;
        #pragma unroll
        for (int e = 0; e < NEXP; ++e) { pr[e] = __expf(lg[e] - mx); se += pr[e]; }
        float inv = 1.f / se;
        #pragma unroll
        for (int e = 0; e < NEXP; ++e) pr[e] *= inv;
        float m2 = -1.f; int a2 = 0;
        #pragma unroll
        for (int e = 0; e < NEXP; ++e) if (e != am && pr[e] > m2) { m2 = pr[e]; a2 = e; }
        float psum = pr[am] + m2;
        if (lane == 0) {
            epack[token] = am | (a2 << 4);
            pw[token * 2] = pr[am] / psum;
            pw[token * 2 + 1] = m2 / psum;
            atomicAdd(&h0S[am], 1);
            atomicAdd(&h1S[a2], 1);
            #pragma unroll
            for (int e = 0; e < NEXP; ++e) prAcc[e] += pr[e];
        }
    }
    if (lane == 0) {
        #pragma unroll
        for (int e = 0; e < NEXP; ++e) atomicAdd(&pS[e], prAcc[e]);
    }
    __syncthreads();
    if (tid < NEXP) {
        H0[blockIdx.x * NEXP + tid] = h0S[tid];
        H1[blockIdx.x * NEXP + tid] = h1S[tid];
        Pblk[blockIdx.x * NEXP + tid] = pS[tid];
    }
}

// ======================= phase 2: scan (1 block) =======================
__global__ __launch_bounds__(256) void scan_k(
    const int* __restrict__ H0, const int* __restrict__ H1,
    const float* __restrict__ Pblk,
    int* __restrict__ bbL, int* __restrict__ counts, int* __restrict__ basep,
    float* __restrict__ aux)
{
    __shared__ int h0S[RB * NEXP], h1S[RB * NEXP], bbS[RB * NEXP];
    __shared__ float pSh[RB * NEXP];
    __shared__ int cS[NEXP], fS[NEXP];
    __shared__ float psS[NEXP];
    int tid = threadIdx.x;
    for (int i = tid; i < RB * NEXP; i += 256) { h0S[i] = H0[i]; h1S[i] = H1[i]; pSh[i] = Pblk[i]; }
    __syncthreads();
    if (tid < NEXP) {
        int run = 0, f = 0; float p = 0.f;
        for (int b = 0; b < RB; ++b) {
            int i = b * NEXP + tid;
            bbS[i] = run;
            run += h0S[i] + h1S[i];
            f += h0S[i];
            p += pSh[i];
        }
        cS[tid] = run; fS[tid] = f; psS[tid] = p;
        counts[tid] = run;
    }
    __syncthreads();
    if (tid == 0) {
        int b = 0; float s = 0.f;
        for (int e = 0; e < NEXP; ++e) {
            basep[e] = b; b += cS[e];
            s += (fS[e] * (1.f / 8192.f)) * (psS[e] * (1.f / 8192.f));
        }
        aux[0] = 0.01f * 8.f * s;
    }
    __syncthreads();
    for (int i = tid; i < RB * NEXP; i += 256) bbL[i] = bbS[i];
}

// ======================= phase 3: scatter (ballot ranking, no atomics) ==============
__global__ __launch_bounds__(256) void scatter_k(
    const int* __restrict__ epack, const int* __restrict__ bbL,
    int* __restrict__ tok_list, int* __restrict__ code)
{
    int tid = threadIdx.x;
    int w = tid >> 6, lane = tid & 63;
    int g = blockIdx.x * 4 + w;
    int token = g * 32 + (lane >> 1);
    int ep = epack[token];
    int e = (lane & 1) ? ((ep >> 4) & 0xF) : (ep & 0xF);
    unsigned long long lower = (lane == 0) ? 0ull : ((~0ull) >> (64 - lane));
    unsigned long long mymask = 0;
    #pragma unroll
    for (int ee = 0; ee < NEXP; ++ee) {
        unsigned long long m = __ballot(e == ee);
        if (ee == e) mymask = m;
    }
    int rank = __popcll(mymask & lower);
    int slot = bbL[g * NEXP + e] + rank;
    tok_list[e * N_TOK + slot] = token;
    code[token * 2 + (lane & 1)] = (e << 13) | slot;
}

// ======================= weight transpose + fp32->bf16 convert =======================
__global__ __launch_bounds__(256) void transpose_cvt_k(const float* __restrict__ in,
                                                       unsigned short* __restrict__ out,
                                                       int R, int C)
{
    __shared__ unsigned short tile[64][72];
    int e = blockIdx.z;
    const float* inp = in + (size_t)e * R * C;
    unsigned short* outp = out + (size_t)e * R * C;
    int r0 = blockIdx.y * 64, c0 = blockIdx.x * 64;
    int tid = threadIdx.x;
    {
        int r = tid >> 2;
        int cseg = (tid & 3) * 16;
        const float* src = inp + (size_t)(r0 + r) * C + c0 + cseg;
        #pragma unroll
        for (int q = 0; q < 4; ++q) {
            float4 v = *(const float4*)(src + q * 4);
            tile[r][cseg + q * 4 + 0] = f2bfbits(v.x);
            tile[r][cseg + q * 4 + 1] = f2bfbits(v.y);
            tile[r][cseg + q * 4 + 2] = f2bfbits(v.z);
            tile[r][cseg + q * 4 + 3] = f2bfbits(v.w);
        }
    }
    __syncthreads();
    {
        int c = tid >> 2;
        int rseg = (tid & 3) * 16;
        unsigned short* dst = outp + (size_t)(c0 + c) * R + r0 + rseg;
        #pragma unroll
        for (int h = 0; h < 2; ++h) {
            u16x8 o;
            #pragma unroll
            for (int i = 0; i < 8; ++i) o[i] = tile[rseg + h * 8 + i][c];
            *(u16x8*)(dst + h * 8) = o;
        }
    }
}

// ======================= grouped MFMA GEMM (async staging, XOR-swizzled LDS) =========
// LDS layout: row r's k-chunk c (8 halfwords) lives at lds[r*32 + (c ^ ((r>>1)&3))*8].
// Staging thread tid writes LDS pos tid*8 (global_load_lds-legal), so it must LOAD
// global chunk (tid&3) ^ ((tid>>3)&3). Fragment reads use pos quad ^ ((row>>1)&3):
// per quad-group, the 8 same-parity lanes spread over all 4 bank groups -> 2-way max.
// SPLITK: grid.z = expert*2+kpart; each kpart covers K/2; partials to O0/O1.
template<bool GATHER, bool RELU, bool SPLITK>
__global__ __launch_bounds__(256) void moe_gemm(
    const unsigned short* __restrict__ A,
    const unsigned short* __restrict__ B,
    unsigned short* __restrict__ O0,
    unsigned short* __restrict__ O1,
    const int* __restrict__ counts,
    const int* __restrict__ basep,
    const int* __restrict__ tok_list,
    const int K, const int N)
{
    int e, koff, steps;
    unsigned short* O;
    if (SPLITK) {
        e = blockIdx.z >> 1;
        int kp = blockIdx.z & 1;
        koff = kp * (K >> 1);
        steps = K >> 6;
        O = kp ? O1 : O0;
    } else {
        e = blockIdx.z; koff = 0; steps = K >> 5; O = O0;
    }
    const int cnt = counts[e];
    const int m0 = blockIdx.y * 128;
    if (m0 >= cnt) return;
    const int n0 = blockIdx.x * 128;
    const int bas = basep[e];

    const int tid = threadIdx.x;
    const int w = tid >> 6, lane = tid & 63;
    const int wr = w >> 1, wc = w & 1;

    __shared__ __align__(16) unsigned short lds[8192];

    // swizzled staging: LDS pos tid&3 <- global chunk (tid&3)^((tid>>3)&3)
    const int kc = ((tid & 3) ^ ((tid >> 3) & 3)) * 8;
    const int r0i = tid >> 2, r1i = 64 + (tid >> 2);
    const unsigned short *aRow0, *aRow1;
    if (GATHER) {
        int s0 = m0 + r0i, s1 = m0 + r1i;
        int t0 = (s0 < cnt) ? tok_list[e * N_TOK + s0] : 0;
        int t1 = (s1 < cnt) ? tok_list[e * N_TOK + s1] : 0;
        aRow0 = A + (size_t)t0 * K + koff + kc;
        aRow1 = A + (size_t)t1 * K + koff + kc;
    } else {
        int s0 = m0 + r0i; if (s0 > cnt - 1) s0 = cnt - 1;
        int s1 = m0 + r1i; if (s1 > cnt - 1) s1 = cnt - 1;
        aRow0 = A + (size_t)(bas + s0) * K + koff + kc;
        aRow1 = A + (size_t)(bas + s1) * K + koff + kc;
    }
    const unsigned short* Be = B + (size_t)e * N * K;
    const unsigned short* bRow0 = Be + (size_t)(n0 + r0i) * K + koff + kc;
    const unsigned short* bRow1 = Be + (size_t)(n0 + r1i) * K + koff + kc;

    f32x4 acc[4][4];
    #pragma unroll
    for (int i = 0; i < 4; ++i)
        #pragma unroll
        for (int j = 0; j < 4; ++j) acc[i][j] = f32x4{0.f, 0.f, 0.f, 0.f};

    const int quad = lane >> 4, ml = lane & 15;
    unsigned short* ldsA0 = &lds[tid * 8];
    unsigned short* ldsA1 = &lds[2048 + tid * 8];
    unsigned short* ldsB0 = &lds[4096 + tid * 8];
    unsigned short* ldsB1 = &lds[6144 + tid * 8];

    // loop-invariant swizzled fragment addresses
    int offA[4], offB[4];
    #pragma unroll
    for (int i = 0; i < 4; ++i) {
        int Ra = wr * 64 + i * 16 + ml;
        offA[i] = Ra * 32 + ((quad ^ ((Ra >> 1) & 3)) * 8);
        int Rb = wc * 64 + i * 16 + ml;
        offB[i] = 4096 + Rb * 32 + ((quad ^ ((Rb >> 1) & 3)) * 8);
    }

    for (int kt = 0; kt < steps; ++kt) {
        const int ko = kt * 32;
        load_lds16(aRow0 + ko, ldsA0);
        load_lds16(aRow1 + ko, ldsA1);
        load_lds16(bRow0 + ko, ldsB0);
        load_lds16(bRow1 + ko, ldsB1);
        __syncthreads();
        bf16x8 af[4], bfr[4];
        #pragma unroll
        for (int i = 0; i < 4; ++i) af[i] = *(const bf16x8*)&lds[offA[i]];
        #pragma unroll
        for (int j = 0; j < 4; ++j) bfr[j] = *(const bf16x8*)&lds[offB[j]];
        #pragma unroll
        for (int i = 0; i < 4; ++i)
            #pragma unroll
            for (int j = 0; j < 4; ++j)
                acc[i][j] = __builtin_amdgcn_mfma_f32_16x16x32_bf16(af[i], bfr[j], acc[i][j], 0, 0, 0);
        __syncthreads();
    }

    #pragma unroll
    for (int i = 0; i < 4; ++i) {
        int rbase = wr * 64 + i * 16 + quad * 4;
        #pragma unroll
        for (int r = 0; r < 4; ++r) {
            int slot = m0 + rbase + r;
            if (slot < cnt) {
                unsigned short* orow = O + (size_t)(bas + slot) * N + n0 + wc * 64 + ml;
                #pragma unroll
                for (int j = 0; j < 4; ++j) {
                    float v = acc[i][j][r];
                    if (RELU) v = v > 0.f ? v : 0.f;
                    orow[j * 16] = f2bfbits(v);
                }
            }
        }
    }
}

// ======================= combine: out[t] = p0*(Y0+Y1)[r0] + p1*(Y0+Y1)[r1] ===========
__global__ __launch_bounds__(256) void combine_k(
    const unsigned short* __restrict__ Y0,
    const unsigned short* __restrict__ Y1,
    const int* __restrict__ code, const float* __restrict__ pw,
    const int* __restrict__ basep,
    float* __restrict__ out)
{
    int t = blockIdx.x;
    int c0 = code[t * 2], c1 = code[t * 2 + 1];
    float p0 = pw[t * 2], p1 = pw[t * 2 + 1];
    size_t r0 = (size_t)(basep[c0 >> 13] + (c0 & 0x1FFF)) * DIM;
    size_t r1 = (size_t)(basep[c1 >> 13] + (c1 & 0x1FFF)) * DIM;
    int d = threadIdx.x * 4;
    u16x4 a0 = *(const u16x4*)(Y0 + r0 + d);
    u16x4 a1 = *(const u16x4*)(Y1 + r0 + d);
    u16x4 b0 = *(const u16x4*)(Y0 + r1 + d);
    u16x4 b1 = *(const u16x4*)(Y1 + r1 + d);
    float4 o;
    o.x = p0 * (bits2f(a0[0]) + bits2f(a1[0])) + p1 * (bits2f(b0[0]) + bits2f(b1[0]));
    o.y = p0 * (bits2f(a0[1]) + bits2f(a1[1])) + p1 * (bits2f(b0[1]) + bits2f(b1[1]));
    o.z = p0 * (bits2f(a0[2]) + bits2f(a1[2])) + p1 * (bits2f(b0[2]) + bits2f(b1[2]));
    o.w = p0 * (bits2f(a0[3]) + bits2f(a1[3])) + p1 * (bits2f(b0[3]) + bits2f(b1[3]));
    *(float4*)(out + (size_t)t * DIM + d) = o;
}

// ======================= launch =======================
extern "C" void kernel_launch(void* const* d_in, const int* in_sizes, int n_in,
                              void* d_out, int out_size, void* d_ws, size_t ws_size,
                              hipStream_t stream)
{
    const float* x    = (const float*)d_in[0];
    const float* gate = (const float*)d_in[1];
    const float* w1   = (const float*)d_in[2];
    const float* w2   = (const float*)d_in[3];
    float* out = (float*)d_out;

    char* ws = (char*)d_ws;
    int*   counts   = (int*)(ws + 0);
    int*   basep    = (int*)(ws + 256);
    int*   epack    = (int*)(ws + 1024);                      // 32 KB
    int*   H0       = (int*)(ws + 1024 + 32768);
    int*   H1       = (int*)(ws + 1024 + 40960);
    float* Pblk     = (float*)(ws + 1024 + 49152);
    int*   bbL      = (int*)(ws + 1024 + 57344);
    int*   tok_list = (int*)(ws + 131072);                    // 256 KB
    int*   code     = (int*)(ws + 131072 + 262144);           // 64 KB
    float* pw       = (float*)(ws + 131072 + 262144 + 65536); // 64 KB
    // big buffers (all bf16):
    //   [1MB, 33MB)   w1t  -> later reused as Yp1 (w1t dead after GEMM1)
    //   [33MB, 65MB)  w2t
    //   [65MB,129MB)  hidden
    //   [129MB,161MB) xb (first 16MB; dead after GEMM1) -> reused as Yp0
    unsigned short* w1t    = (unsigned short*)(ws + (1 << 20));
    unsigned short* w2t    = (unsigned short*)(ws + (1 << 20) + 33554432);
    unsigned short* hidden = (unsigned short*)(ws + (1 << 20) + 67108864);
    unsigned short* xb     = (unsigned short*)(ws + (1 << 20) + 134217728);
    unsigned short* Yp0    = xb;    // GEMM2 kpart0 partials (xb dead by then)
    unsigned short* Yp1    = w1t;   // GEMM2 kpart1 partials (w1t dead by then)

    route_k<<<RB, 512, 0, stream>>>(x, gate, epack, pw, xb, H0, H1, Pblk);
    scan_k<<<1, 256, 0, stream>>>(H0, H1, Pblk, bbL, counts, basep, out + (size_t)N_TOK * DIM);
    scatter_k<<<64, 256, 0, stream>>>(epack, bbL, tok_list, code);
    transpose_cvt_k<<<dim3(HID / 64, DIM / 64, NEXP), 256, 0, stream>>>(w1, w1t, DIM, HID);
    transpose_cvt_k<<<dim3(DIM / 64, HID / 64, NEXP), 256, 0, stream>>>(w2, w2t, HID, DIM);
    moe_gemm<true, true, false><<<dim3(HID / 128, 64, NEXP), 256, 0, stream>>>(
        xb, w1t, hidden, nullptr, counts, basep, tok_list, DIM, HID);
    moe_gemm<false, false, true><<<dim3(DIM / 128, 64, NEXP * 2), 256, 0, stream>>>(
        hidden, w2t, Yp0, Yp1, counts, basep, tok_list, HID, DIM);
    combine_k<<<N_TOK, 256, 0, stream>>>(Yp0, Yp1, code, pw, basep, out);
}